// Round 8
// baseline (271.327 us; speedup 1.0000x reference)
//
#include <hip/hip_runtime.h>

// MultiHeadedAttention (B=8, S=1024, D=512, H=8, DK=DV=64), f32 in/out.
// r8: bf16 pre-convert of activations + m97-style GEMMs (global_load_lds w=16,
// XOR-swizzled unpadded A-tile, 2-barrier K-loop). V-GEMM writes Vt directly
// (LDS-transposed epilogue) — vt kernel deleted. attn unchanged from r7.
// Memory: d_out = [Xq_b | Xk_b] -> [Vt | Xk_b] -> final f32 out.
//         ws    = [Xv_b->Cw | Qd | Kw]  (exactly 3 mats = proven budget).

typedef unsigned short u16;
typedef u16 u16x4 __attribute__((ext_vector_type(4)));
typedef u16 u16x8 __attribute__((ext_vector_type(8)));
typedef short s16x8 __attribute__((ext_vector_type(8)));
typedef float f32x4 __attribute__((ext_vector_type(4)));

#define SB 1024
#define DD 512
#define NEGC (-1.0e9f)

__device__ __forceinline__ float bf2f(u16 x) {
    return __uint_as_float(((unsigned)x) << 16);
}
__device__ __forceinline__ u16 f2bf(float f) {
    unsigned u = __float_as_uint(f);
    u += 0x7FFFu + ((u >> 16) & 1u);
    return (u16)(u >> 16);
}

// async global->LDS, 16B per lane; dest = wave-uniform base + lane*16
__device__ __forceinline__ void glds16(const void* g, void* l) {
    __builtin_amdgcn_global_load_lds(
        (const __attribute__((address_space(1))) void*)g,
        (__attribute__((address_space(3))) void*)l, 16, 0, 0);
}

// DPP 16-lane-row reduce (pure VALU)
template<int CTRL>
__device__ __forceinline__ float dppf(float x) {
    return __int_as_float(__builtin_amdgcn_mov_dpp(__float_as_int(x), CTRL, 0xF, 0xF, true));
}
__device__ __forceinline__ float row16_max(float x) {
    x = fmaxf(x, dppf<0xB1>(x));
    x = fmaxf(x, dppf<0x4E>(x));
    x = fmaxf(x, dppf<0x141>(x));
    x = fmaxf(x, dppf<0x140>(x));
    return x;
}
__device__ __forceinline__ float row16_sum(float x) {
    x += dppf<0xB1>(x);
    x += dppf<0x4E>(x);
    x += dppf<0x141>(x);
    x += dppf<0x140>(x);
    return x;
}

// ---------------------------------------------------------------------------
// f32 -> bf16 conversion pass (grid (mat/2048, 3))
// ---------------------------------------------------------------------------
__global__ __launch_bounds__(256) void cvt_kernel(
    const float* __restrict__ s0, const float* __restrict__ s1, const float* __restrict__ s2,
    u16* __restrict__ d0, u16* __restrict__ d1, u16* __restrict__ d2)
{
    const int z = blockIdx.y;
    const float* s = (z == 0) ? s0 : (z == 1) ? s1 : s2;
    u16* d = (z == 0) ? d0 : (z == 1) ? d1 : d2;
    const size_t i = ((size_t)blockIdx.x * 256 + threadIdx.x) * 8;
    f32x4 a = *(const f32x4*)(s + i);
    f32x4 b = *(const f32x4*)(s + i + 4);
    u16x8 o;
    #pragma unroll
    for (int e = 0; e < 4; ++e) { o[e] = f2bf(a[e]); o[4 + e] = f2bf(b[e]); }
    *(u16x8*)(d + i) = o;
}

// ---------------------------------------------------------------------------
// GEMM core: C[m][n] = (sum_k X[m][k]*W[n][k] + bias[n]) * scale
// X bf16 (global_load_lds staging, XOR-swizzled chunks), W f32 (cvt at stage).
// Tile 128(M)x64(N), BK=64, 4 waves (wave-tile 32x64, 2x4 acc).
// MODE: 0 = bf16 out row-major, 1 = f32 out row-major,
//       2 = bf16 out transposed to Vt[(b*8+h)*64+dv][tok] via LDS.
// ---------------------------------------------------------------------------
template<int MODE>
__device__ __forceinline__ void gemm_core(
    const u16* __restrict__ X, const float* __restrict__ W,
    const float* __restrict__ bias, void* __restrict__ Cv, u16* __restrict__ Vt,
    int M, int N, int K, float scale)
{
    __shared__ __align__(16) u16 As[128][64];   // UNPADDED (glds dest), XOR-swizzled chunks
    __shared__ __align__(16) u16 Bs[64][72];    // padded (ds_write path)
    const int tid  = threadIdx.x;
    const int lane = tid & 63, wave = tid >> 6;
    const int l15 = lane & 15, lq = lane >> 4;

    // XCD swizzle: l%8 = xcd; consecutive j on one xcd sweep N for one M-slab
    const int l   = blockIdx.x + gridDim.x * blockIdx.y;
    const int xcd = l & 7, j = l >> 3;
    const int m0  = (xcd * 8 + (j >> 3)) * 128;   // M/128 = 64 slabs
    const int n0  = (j & 7) * 64;

    // A staging: wave w, instr i covers rows w*32+i*8 .. +8; lane -> row lane>>3,
    // source chunk (lane&7)^(lane>>3) (XOR swizzle so frag reads are 2-way/bank)
    const int l8 = lane >> 3;
    const int c8 = (lane & 7) ^ l8;
    const u16* xlane = X + (size_t)(m0 + wave * 32 + l8) * K + c8 * 8;

    // W staging: chunk c = i*256+tid -> row c>>4, col (c&15)*4
    int wr_[4], wc_[4];
    #pragma unroll
    for (int i = 0; i < 4; ++i) {
        int c = i * 256 + tid;
        wr_[i] = c >> 4;  wc_[i] = (c & 15) * 4;
    }

    f32x4 wa[4];
    auto load_w = [&](int k0) {
        #pragma unroll
        for (int i = 0; i < 4; ++i)
            wa[i] = *(const f32x4*)(W + (size_t)(n0 + wr_[i]) * K + k0 + wc_[i]);
    };

    f32x4 acc[2][4] = {};
    load_w(0);
    const int steps = K / 64;
    for (int kt = 0; kt < steps; ++kt) {
        const int k0 = kt * 64;
        __syncthreads();   // (1) all frag reads of prev tile done
        #pragma unroll
        for (int i = 0; i < 4; ++i)
            glds16(xlane + (size_t)(i * 8) * K + k0, &As[wave * 32 + i * 8][0]);
        #pragma unroll
        for (int i = 0; i < 4; ++i) {
            u16x4 t;
            #pragma unroll
            for (int e = 0; e < 4; ++e) t[e] = f2bf(wa[i][e]);
            *(u16x4*)&Bs[wr_[i]][wc_[i]] = t;
        }
        __syncthreads();   // (2) publish (drains glds vmcnt + lds writes)
        if (kt + 1 < steps) load_w(k0 + 64);

        #pragma unroll
        for (int ks = 0; ks < 2; ++ks) {
            s16x8 af[2], bf[4];
            #pragma unroll
            for (int mt = 0; mt < 2; ++mt) {
                const int row = wave * 32 + mt * 16 + l15;
                af[mt] = *(const s16x8*)&As[row][((ks * 4 + lq) ^ (l15 & 7)) * 8];
            }
            #pragma unroll
            for (int nt = 0; nt < 4; ++nt)
                bf[nt] = *(const s16x8*)&Bs[nt * 16 + l15][ks * 32 + lq * 8];
            #pragma unroll
            for (int mt = 0; mt < 2; ++mt)
                #pragma unroll
                for (int nt = 0; nt < 4; ++nt)
                    acc[mt][nt] = __builtin_amdgcn_mfma_f32_16x16x32_bf16(
                        af[mt], bf[nt], acc[mt][nt], 0, 0, 0);
        }
    }

    float bb[4];
    #pragma unroll
    for (int nt = 0; nt < 4; ++nt) bb[nt] = bias[n0 + nt * 16 + l15];

    if (MODE == 2) {
        // transpose epilogue -> Vt[(b*8+h)*64+dv][tok]
        __shared__ __align__(16) u16 Ts[64][132];
        #pragma unroll
        for (int mt = 0; mt < 2; ++mt)
            #pragma unroll
            for (int r = 0; r < 4; ++r)
                #pragma unroll
                for (int nt = 0; nt < 4; ++nt)
                    Ts[nt * 16 + l15][wave * 32 + mt * 16 + lq * 4 + r] =
                        f2bf((acc[mt][nt][r] + bb[nt]) * scale);
        __syncthreads();
        const int b_ = m0 >> 10, tok0 = m0 & 1023, h = n0 >> 6;
        const int dv = tid >> 2, seg = tid & 3;
        u16* dst = Vt + ((size_t)(b_ * 8 + h) * 64 + dv) * SB + tok0 + seg * 32;
        #pragma unroll
        for (int e = 0; e < 4; ++e)
            *(u16x8*)(dst + e * 8) = *(const u16x8*)&Ts[dv][seg * 32 + e * 8];
    } else {
        #pragma unroll
        for (int mt = 0; mt < 2; ++mt) {
            #pragma unroll
            for (int r = 0; r < 4; ++r) {
                const size_t row = (size_t)(m0 + wave * 32 + mt * 16 + lq * 4 + r);
                #pragma unroll
                for (int nt = 0; nt < 4; ++nt) {
                    float v = (acc[mt][nt][r] + bb[nt]) * scale;
                    const size_t col = n0 + nt * 16 + l15;
                    if (MODE == 1) ((float*)Cv)[row * N + col] = v;
                    else           ((u16*)Cv)[row * N + col] = f2bf(v);
                }
            }
        }
    }
}

__global__ __launch_bounds__(256) void qk_gemm(
    const u16* __restrict__ Xq, const u16* __restrict__ Xk,
    const float* __restrict__ Wq, const float* __restrict__ Wk,
    const float* __restrict__ bq, const float* __restrict__ bk,
    u16* __restrict__ Cq, u16* __restrict__ Ck)
{
    const int z = blockIdx.z;
    const u16* X = z ? Xk : Xq;
    const float* W = z ? Wk : Wq;
    const float* b = z ? bk : bq;
    u16* C = z ? Ck : Cq;
    const float sc = z ? 1.0f : 0.125f;
    gemm_core<0>(X, W, b, C, nullptr, 8 * SB, DD, DD, sc);
}

__global__ __launch_bounds__(256) void v_gemm(
    const u16* __restrict__ Xv, const float* __restrict__ Wv,
    const float* __restrict__ bv, u16* __restrict__ Vt)
{
    gemm_core<2>(Xv, Wv, bv, nullptr, Vt, 8 * SB, DD, DD, 1.0f);
}

__global__ __launch_bounds__(256) void out_gemm(
    const u16* __restrict__ Xc, const float* __restrict__ Wo,
    const float* __restrict__ bo, float* __restrict__ C)
{
    gemm_core<1>(Xc, Wo, bo, C, nullptr, 8 * SB, DD, DD, 1.0f);
}

// ---------------------------------------------------------------------------
// Flash attention (unchanged from r7; 62 us proven). Grid (8,8,8), 4 waves,
// wave owns 32 q-rows; dbuf K/V staging 1 barrier/iter; maps direct-global;
// DPP max reduce; deferred l-sum; per-wave P LDS round-trip.
// ---------------------------------------------------------------------------
__global__ __launch_bounds__(256, 2) void attn_mfma(
    const u16* __restrict__ Qg, const u16* __restrict__ Kg,
    const u16* __restrict__ Vt,
    const float* __restrict__ itg, const float* __restrict__ istg,
    const float* __restrict__ dfg,
    u16* __restrict__ Cg)
{
    const int h  = blockIdx.y;
    const int b  = blockIdx.z;
    const int tid = threadIdx.x;
    const int lane = tid & 63, w = tid >> 6;
    const int l15 = lane & 15, lq = lane >> 4;
    const int qw = blockIdx.x * 128 + w * 32;

    __shared__ __align__(16) u16 Ks[2][64][72];
    __shared__ __align__(16) u16 Vs[2][64][72];
    __shared__ __align__(16) u16 Pb[4][32][72];

    int krow[2], kcol[2];
    #pragma unroll
    for (int i = 0; i < 2; ++i) {
        int c = i * 256 + tid;
        krow[i] = c >> 3;
        kcol[i] = (c & 7) * 8;
    }

    const bool domaps = (h < 6);
    const float* mapsel = (h < 2) ? itg : (h < 4) ? istg : dfg;
    const float* mpp[8];
    #pragma unroll
    for (int qt = 0; qt < 2; ++qt)
        #pragma unroll
        for (int r = 0; r < 4; ++r)
            mpp[qt * 4 + r] = mapsel + ((size_t)b * SB + qw + qt * 16 + lq * 4 + r) * SB + l15;

    s16x8 aq[2][2];
    #pragma unroll
    for (int qt = 0; qt < 2; ++qt) {
        const u16* qp = Qg + (size_t)(b * SB + qw + qt * 16 + l15) * DD + h * 64 + lq * 8;
        aq[qt][0] = *(const s16x8*)qp;
        aq[qt][1] = *(const s16x8*)(qp + 32);
    }

    u16x8 kr[2], vr[2];
    auto load_kv = [&](int k0) {
        #pragma unroll
        for (int i = 0; i < 2; ++i) {
            kr[i] = *(const u16x8*)(Kg + (size_t)(b * SB + k0 + krow[i]) * DD + h * 64 + kcol[i]);
            vr[i] = *(const u16x8*)(Vt + ((size_t)(b * 8 + h) * 64 + krow[i]) * SB + k0 + kcol[i]);
        }
    };
    float mc[32];
    auto load_maps = [&]() {
        #pragma unroll
        for (int i = 0; i < 8; ++i) {
            #pragma unroll
            for (int nt = 0; nt < 4; ++nt)
                mc[i * 4 + nt] = mpp[i][nt * 16];
            mpp[i] += 64;
        }
    };

    f32x4 ctx[2][4] = {};
    float m_i[8], lp[8];
    #pragma unroll
    for (int i = 0; i < 8; ++i) { m_i[i] = -3.0e38f; lp[i] = 0.0f; }

    load_kv(0);
    if (domaps) load_maps();

    for (int kt = 0; kt < 16; ++kt) {
        const int buf = kt & 1;
        #pragma unroll
        for (int i = 0; i < 2; ++i) {
            *(u16x8*)&Ks[buf][krow[i]][kcol[i]] = kr[i];
            *(u16x8*)&Vs[buf][krow[i]][kcol[i]] = vr[i];
        }
        __syncthreads();
        if (kt + 1 < 16) load_kv((kt + 1) * 64);

        f32x4 S[2][4];
        #pragma unroll
        for (int nt = 0; nt < 4; ++nt) {
            s16x8 b0 = *(const s16x8*)&Ks[buf][nt * 16 + l15][lq * 8];
            s16x8 b1 = *(const s16x8*)&Ks[buf][nt * 16 + l15][32 + lq * 8];
            #pragma unroll
            for (int qt = 0; qt < 2; ++qt) {
                f32x4 s = {};
                s = __builtin_amdgcn_mfma_f32_16x16x32_bf16(aq[qt][0], b0, s, 0, 0, 0);
                s = __builtin_amdgcn_mfma_f32_16x16x32_bf16(aq[qt][1], b1, s, 0, 0, 0);
                S[qt][nt] = s;
            }
        }

        if (h < 4) {
            #pragma unroll
            for (int qt = 0; qt < 2; ++qt)
                #pragma unroll
                for (int nt = 0; nt < 4; ++nt)
                    #pragma unroll
                    for (int r = 0; r < 4; ++r)
                        S[qt][nt][r] += NEGC * mc[(qt * 4 + r) * 4 + nt];
        } else if (h < 6) {
            #pragma unroll
            for (int qt = 0; qt < 2; ++qt)
                #pragma unroll
                for (int nt = 0; nt < 4; ++nt)
                    #pragma unroll
                    for (int r = 0; r < 4; ++r)
                        S[qt][nt][r] *= (1.0f + 5.0f * mc[(qt * 4 + r) * 4 + nt]);
        }
        if (domaps && kt + 1 < 16) load_maps();

        #pragma unroll
        for (int qt = 0; qt < 2; ++qt) {
            #pragma unroll
            for (int r = 0; r < 4; ++r) {
                const int i = qt * 4 + r;
                float rm = fmaxf(fmaxf(S[qt][0][r], S[qt][1][r]),
                                 fmaxf(S[qt][2][r], S[qt][3][r]));
                rm = row16_max(rm);
                float mn = fmaxf(m_i[i], rm);
                float al = __expf(m_i[i] - mn);
                m_i[i] = mn;
                float ls = 0.0f;
                #pragma unroll
                for (int nt = 0; nt < 4; ++nt) {
                    float p = __expf(S[qt][nt][r] - mn);
                    S[qt][nt][r] = p;
                    ls += p;
                }
                lp[i] = lp[i] * al + ls;
                #pragma unroll
                for (int nt = 0; nt < 4; ++nt) ctx[qt][nt][r] *= al;
            }
        }

        #pragma unroll
        for (int qt = 0; qt < 2; ++qt)
            #pragma unroll
            for (int nt = 0; nt < 4; ++nt)
                #pragma unroll
                for (int r = 0; r < 4; ++r)
                    Pb[w][qt * 16 + lq * 4 + r][nt * 16 + l15] = f2bf(S[qt][nt][r]);
        s16x8 ap[2][2];
        #pragma unroll
        for (int qt = 0; qt < 2; ++qt) {
            ap[qt][0] = *(const s16x8*)&Pb[w][qt * 16 + l15][lq * 8];
            ap[qt][1] = *(const s16x8*)&Pb[w][qt * 16 + l15][32 + lq * 8];
        }

        #pragma unroll
        for (int dvt = 0; dvt < 4; ++dvt) {
            s16x8 b0 = *(const s16x8*)&Vs[buf][dvt * 16 + l15][lq * 8];
            s16x8 b1 = *(const s16x8*)&Vs[buf][dvt * 16 + l15][32 + lq * 8];
            #pragma unroll
            for (int qt = 0; qt < 2; ++qt) {
                ctx[qt][dvt] = __builtin_amdgcn_mfma_f32_16x16x32_bf16(ap[qt][0], b0, ctx[qt][dvt], 0, 0, 0);
                ctx[qt][dvt] = __builtin_amdgcn_mfma_f32_16x16x32_bf16(ap[qt][1], b1, ctx[qt][dvt], 0, 0, 0);
            }
        }
    }

    #pragma unroll
    for (int qt = 0; qt < 2; ++qt) {
        #pragma unroll
        for (int r = 0; r < 4; ++r) {
            const int i = qt * 4 + r;
            float l = row16_sum(lp[i]);
            float inv = (l > 0.0f) ? (1.0f / l) : 0.0f;
            #pragma unroll
            for (int dvt = 0; dvt < 4; ++dvt)
                Cg[(size_t)(b * SB + qw + qt * 16 + lq * 4 + r) * DD + h * 64 + dvt * 16 + l15] =
                    f2bf(ctx[qt][dvt][r] * inv);
        }
    }
}

extern "C" void kernel_launch(void* const* d_in, const int* in_sizes, int n_in,
                              void* d_out, int out_size, void* d_ws, size_t ws_size,
                              hipStream_t stream) {
    const float* key   = (const float*)d_in[0];
    const float* value = (const float*)d_in[1];
    const float* query = (const float*)d_in[2];
    const float* itg   = (const float*)d_in[3];
    const float* istg  = (const float*)d_in[4];
    const float* dfg   = (const float*)d_in[5];
    const float* Wq = (const float*)d_in[7];   const float* bq = (const float*)d_in[8];
    const float* Wk = (const float*)d_in[9];   const float* bk = (const float*)d_in[10];
    const float* Wv = (const float*)d_in[11];  const float* bv = (const float*)d_in[12];
    const float* Wo = (const float*)d_in[13];  const float* bo = (const float*)d_in[14];

    const size_t mat = (size_t)8 * SB * DD;          // 4,194,304 elems
    if (ws_size < 3 * mat * sizeof(u16)) return;     // proven satisfied (r3)

    // region plan (each slot = one bf16 mat, 8 MiB):
    u16* XqB = (u16*)d_out;          // d_out slot 0: Xq_b, later Vt
    u16* XkB = XqB + mat;            // d_out slot 1: Xk_b (dead after K-GEMM)
    u16* XvB = (u16*)d_ws;           // ws A: Xv_b, later Cw
    u16* Qd  = XvB + mat;            // ws B
    u16* Kw  = Qd + mat;             // ws C
    u16* VtB = XqB;                  // Vt overwrites Xq_b (after QK-GEMM)
    u16* Cw  = XvB;                  // Cw overwrites Xv_b (after V-GEMM)

    cvt_kernel<<<dim3(mat / 2048, 3), 256, 0, stream>>>(query, key, value, XqB, XkB, XvB);
    qk_gemm<<<dim3(8, 64, 2), 256, 0, stream>>>(XqB, XkB, Wq, Wk, bq, bk, Qd, Kw);
    v_gemm<<<dim3(8, 64), 256, 0, stream>>>(XvB, Wv, bv, VtB);
    attn_mfma<<<dim3(SB / 128, 8, 8), 256, 0, stream>>>(Qd, Kw, VtB, itg, istg, dfg, Cw);
    out_gemm<<<dim3(8, 64), 256, 0, stream>>>(Cw, Wo, bo, (float*)d_out);
}